// Round 2
// baseline (429.573 us; speedup 1.0000x reference)
//
#include <hip/hip_runtime.h>
#include <hip/hip_bf16.h>

#define GN 8192
#define KD 256
#define OD 64
#define LOG2E 1.44269504f
#define NCH2 32    // k2: 32 chunks x 256 j = full 8192-j row per block

typedef __attribute__((ext_vector_type(8))) short bf16x8;
typedef __attribute__((ext_vector_type(4))) float f32x4;

__device__ __forceinline__ float fexp2(float x) {
#if __has_builtin(__builtin_amdgcn_exp2f)
  return __builtin_amdgcn_exp2f(x);
#else
  return exp2f(x);
#endif
}

// ---------------------------------------------------------------------------
// Kernel 1 REWRITE: h = input @ W (fp32 accum, unchanged numerics).
// Old version was LDS-throughput-bound (~12.8 us: W broadcast reads via
// ds_read_b128 burned 30 LDS cyc/wave-iter at 1 wave/SIMD). New structure:
//  - 128 blocks x 64 rows; lane = row, wave wv owns cols [wv*16, wv*16+16).
//  - W is read at a WAVE-UNIFORM address (wv via readfirstlane) -> compiler
//    scalarizes to s_load (scalar cache, parallel pipe). Zero LDS for W.
//  - input row staged in LDS with ODD stride 261: read inT[lane*261+k] is
//    bank-conflict-free (261%32=5, coprime). Staging writes are 8-way
//    conflicted b32 but only 16K writes total (~0.3 us).
//  - hot loop: 1 ds_read_b32 + 16 v_fmac (SGPR W operand) -> VALU-bound,
//    ~4 us instead of 12.8.
// f1/f2 computed fp32 from the fp32 accumulators (same as before); hTt
// written bf16 in the tiled [j/32][col][j%32] layout via LDS transpose
// (reusing inT) for coalesced 16B stores.
// ---------------------------------------------------------------------------
__global__ __launch_bounds__(256) void gat_k1(
    const float* __restrict__ input, const float* __restrict__ W,
    const float* __restrict__ a, __hip_bfloat16* __restrict__ hTt,
    float* __restrict__ f1p, float* __restrict__ f2p, float* __restrict__ out)
{
  __shared__ float inT[64 * 261];      // 66.8 KB
  __shared__ float red1[4][64];
  __shared__ float red2[4][64];
  __shared__ float s1row[64];
  __shared__ float s2row[64];

  const int tid = threadIdx.x;
  const int lane = tid & 63;
  const int wv = __builtin_amdgcn_readfirstlane(tid >> 6);
  const int i0 = blockIdx.x * 64;

  // stage 64 input rows (64 KB) into LDS, row-major stride 261
#pragma unroll
  for (int it = 0; it < 16; ++it) {
    int idx = tid + it * 256;
    int r = idx >> 6, k4 = idx & 63;
    float4 v = *(const float4*)(input + (long)(i0 + r) * KD + k4 * 4);
    float* d = &inT[r * 261 + k4 * 4];
    d[0] = v.x; d[1] = v.y; d[2] = v.z; d[3] = v.w;
  }
  __syncthreads();

  const float* __restrict__ Wp = W + wv * 16;   // wave-uniform -> s_load
  const float* inrow = &inT[lane * 261];
  float acc[16];
#pragma unroll
  for (int i = 0; i < 16; ++i) acc[i] = 0.f;

#pragma unroll 2
  for (int k = 0; k < KD; ++k) {
    float inv = inrow[k];
    float4 w0 = *(const float4*)(Wp + k * 64 + 0);
    float4 w1 = *(const float4*)(Wp + k * 64 + 4);
    float4 w2 = *(const float4*)(Wp + k * 64 + 8);
    float4 w3 = *(const float4*)(Wp + k * 64 + 12);
    acc[0]  += inv * w0.x; acc[1]  += inv * w0.y;
    acc[2]  += inv * w0.z; acc[3]  += inv * w0.w;
    acc[4]  += inv * w1.x; acc[5]  += inv * w1.y;
    acc[6]  += inv * w1.z; acc[7]  += inv * w1.w;
    acc[8]  += inv * w2.x; acc[9]  += inv * w2.y;
    acc[10] += inv * w2.z; acc[11] += inv * w2.w;
    acc[12] += inv * w3.x; acc[13] += inv * w3.y;
    acc[14] += inv * w3.z; acc[15] += inv * w3.w;
  }

  // f1/f2 partials (fp32, from fp32 accs; a[] loads are wave-uniform)
  float s1 = 0.f, s2 = 0.f;
#pragma unroll
  for (int i = 0; i < 16; ++i) {
    s1 += acc[i] * a[wv * 16 + i];
    s2 += acc[i] * a[OD + wv * 16 + i];
  }
  red1[wv][lane] = s1; red2[wv][lane] = s2;
  __syncthreads();                     // inT reads also complete here

  if (tid < 64) {
    float f1 = red1[0][tid] + red1[1][tid] + red1[2][tid] + red1[3][tid];
    float f2 = red2[0][tid] + red2[1][tid] + red2[2][tid] + red2[3][tid];
    s1row[tid] = f1; s2row[tid] = f2;
    f1p[i0 + tid] = f1 * LOG2E;
    f2p[i0 + tid] = f2 * LOG2E;
  }

  // h -> bf16 tiled hTt via LDS transpose (reuse inT: safe after barrier)
  __hip_bfloat16* sT = (__hip_bfloat16*)inT;     // [64 cols][72 rows]
#pragma unroll
  for (int i = 0; i < 16; ++i)
    sT[(wv * 16 + i) * 72 + lane] = __float2bfloat16(acc[i]);
  __syncthreads();

  {
    int jt = tid >> 7;                  // 0..1 (two 32-j tiles per block)
    int col = (tid >> 1) & 63;
    int jm0 = (tid & 1) * 16;
    const int4* sp =
        (const int4*)((const unsigned short*)inT + col * 72 + jt * 32 + jm0);
    int4 p0 = sp[0], p1 = sp[1];
    int4* dst = (int4*)(hTt + (long)blockIdx.x * 4096 + jt * 2048 + col * 32 + jm0);
    dst[0] = p0; dst[1] = p1;
  }

  if (blockIdx.x == 0 && tid == 0) {
    float e12 = s1row[1] + s2row[2];
    float e13 = s1row[1] + s2row[3];
    float e32 = s1row[3] + s2row[2];
    out[(long)GN * OD + 0] = fmaxf(e12, 0.01f * e12);
    out[(long)GN * OD + 1] = fmaxf(e13, 0.01f * e13);
    out[(long)GN * OD + 2] = fmaxf(e32, 0.01f * e32);
  }
}

// ---------------------------------------------------------------------------
// Kernel 2: fused mask+softmax(no-max)+alpha@h, now over the FULL 8192-j row
// per block (512 blocks x 16 rows). num/den complete per block -> writes
// final out = num/den directly; k3 and the pn/pd partial traffic are gone.
// Barrier-free main loop (r1-proven neutral-vs-staged => adj-BW-bound);
// direct int4 adj gathers, B-frags from tiled hTt (L2-resident).
// ---------------------------------------------------------------------------
__global__ __launch_bounds__(256, 2) void gat_k2(
    const int* __restrict__ adj, const __hip_bfloat16* __restrict__ hTt,
    const float* __restrict__ f1p, const float* __restrict__ f2p,
    float* __restrict__ out)
{
  __shared__ float f2l[8192];          // 32 KB full f2 row
  __shared__ float pb[4 * 16 * 68];    // 17.4 KB wave K-partials
  __shared__ float sb[64];             // row-sum partials

  const int tid = threadIdx.x;
  const int lane = tid & 63;
  const int wv = tid >> 6;             // wave -> k-steps {2wv, 2wv+1}
  const int tn = lane & 15;
  const int quad = lane >> 4;
  const int i0 = blockIdx.x * 16;

  // stage full f2 row (32 KB)
  for (int i = tid; i < 8192 / 4; i += 256)
    ((float4*)f2l)[i] = ((const float4*)f2p)[i];

  const float f1r = f1p[i0 + tn];

  // per-wave j-offsets within a 256-j chunk
  const int jo0 = wv * 64 + quad * 8;
  const int jo1 = jo0 + 32;
  const int* __restrict__ adjr = adj + (long)(i0 + tn) * GN;
  const __hip_bfloat16* hsl = hTt + tn * 32 + quad * 8;

  f32x4 acc[4];
#pragma unroll
  for (int nf = 0; nf < 4; ++nf) acc[nf] = (f32x4){0.f, 0.f, 0.f, 0.f};
  f32x4 accS = (f32x4){0.f, 0.f, 0.f, 0.f};

  bf16x8 ones;  // ones in column n==0 -> row sums via MFMA
  {
    short ov = (tn == 0) ? (short)0x3F80 : (short)0;
#pragma unroll
    for (int i = 0; i < 8; ++i) ones[i] = ov;
  }

  __syncthreads();  // f2l ready; no barriers until epilogue

  for (int c = 0; c < NCH2; ++c) {
    const int* ap = adjr + c * 256;
    const int4 a0 = *(const int4*)(ap + jo0);
    const int4 a1 = *(const int4*)(ap + jo0 + 4);
    const int4 a2 = *(const int4*)(ap + jo1);
    const int4 a3 = *(const int4*)(ap + jo1 + 4);

    const __hip_bfloat16* h0 = hsl + (long)(c * 8 + 2 * wv) * (OD * 32);
    const __hip_bfloat16* h1 = h0 + (OD * 32);
    bf16x8 B0[4], B1[4];
#pragma unroll
    for (int nf = 0; nf < 4; ++nf) {
      B0[nf] = *(const bf16x8*)(h0 + nf * (16 * 32));
      B1[nf] = *(const bf16x8*)(h1 + nf * (16 * 32));
    }

    const float4 f20 = *(const float4*)&f2l[c * 256 + jo0];
    const float4 f21 = *(const float4*)&f2l[c * 256 + jo0 + 4];
    const float4 f22 = *(const float4*)&f2l[c * 256 + jo1];
    const float4 f23 = *(const float4*)&f2l[c * 256 + jo1 + 4];

    union { bf16x8 v; unsigned u[4]; } w0, w1;
    {
      float e0 = f1r + f20.x, e1 = f1r + f20.y, e2 = f1r + f20.z, e3 = f1r + f20.w;
      float e4 = f1r + f21.x, e5 = f1r + f21.y, e6 = f1r + f21.z, e7 = f1r + f21.w;
      float v0 = fexp2((a0.x > 0) ? fmaxf(e0, 0.01f * e0) : -256.f);
      float v1 = fexp2((a0.y > 0) ? fmaxf(e1, 0.01f * e1) : -256.f);
      float v2 = fexp2((a0.z > 0) ? fmaxf(e2, 0.01f * e2) : -256.f);
      float v3 = fexp2((a0.w > 0) ? fmaxf(e3, 0.01f * e3) : -256.f);
      float v4 = fexp2((a1.x > 0) ? fmaxf(e4, 0.01f * e4) : -256.f);
      float v5 = fexp2((a1.y > 0) ? fmaxf(e5, 0.01f * e5) : -256.f);
      float v6 = fexp2((a1.z > 0) ? fmaxf(e6, 0.01f * e6) : -256.f);
      float v7 = fexp2((a1.w > 0) ? fmaxf(e7, 0.01f * e7) : -256.f);
      w0.u[0] = __builtin_amdgcn_perm(__float_as_uint(v1), __float_as_uint(v0), 0x07060302u);
      w0.u[1] = __builtin_amdgcn_perm(__float_as_uint(v3), __float_as_uint(v2), 0x07060302u);
      w0.u[2] = __builtin_amdgcn_perm(__float_as_uint(v5), __float_as_uint(v4), 0x07060302u);
      w0.u[3] = __builtin_amdgcn_perm(__float_as_uint(v7), __float_as_uint(v6), 0x07060302u);
    }
    {
      float e0 = f1r + f22.x, e1 = f1r + f22.y, e2 = f1r + f22.z, e3 = f1r + f22.w;
      float e4 = f1r + f23.x, e5 = f1r + f23.y, e6 = f1r + f23.z, e7 = f1r + f23.w;
      float v0 = fexp2((a2.x > 0) ? fmaxf(e0, 0.01f * e0) : -256.f);
      float v1 = fexp2((a2.y > 0) ? fmaxf(e1, 0.01f * e1) : -256.f);
      float v2 = fexp2((a2.z > 0) ? fmaxf(e2, 0.01f * e2) : -256.f);
      float v3 = fexp2((a2.w > 0) ? fmaxf(e3, 0.01f * e3) : -256.f);
      float v4 = fexp2((a3.x > 0) ? fmaxf(e4, 0.01f * e4) : -256.f);
      float v5 = fexp2((a3.y > 0) ? fmaxf(e5, 0.01f * e5) : -256.f);
      float v6 = fexp2((a3.z > 0) ? fmaxf(e6, 0.01f * e6) : -256.f);
      float v7 = fexp2((a3.w > 0) ? fmaxf(e7, 0.01f * e7) : -256.f);
      w1.u[0] = __builtin_amdgcn_perm(__float_as_uint(v1), __float_as_uint(v0), 0x07060302u);
      w1.u[1] = __builtin_amdgcn_perm(__float_as_uint(v3), __float_as_uint(v2), 0x07060302u);
      w1.u[2] = __builtin_amdgcn_perm(__float_as_uint(v5), __float_as_uint(v4), 0x07060302u);
      w1.u[3] = __builtin_amdgcn_perm(__float_as_uint(v7), __float_as_uint(v6), 0x07060302u);
    }

#pragma unroll
    for (int nf = 0; nf < 4; ++nf)
      acc[nf] = __builtin_amdgcn_mfma_f32_16x16x32_bf16(w0.v, B0[nf], acc[nf], 0, 0, 0);
    accS = __builtin_amdgcn_mfma_f32_16x16x32_bf16(w0.v, ones, accS, 0, 0, 0);
#pragma unroll
    for (int nf = 0; nf < 4; ++nf)
      acc[nf] = __builtin_amdgcn_mfma_f32_16x16x32_bf16(w1.v, B1[nf], acc[nf], 0, 0, 0);
    accS = __builtin_amdgcn_mfma_f32_16x16x32_bf16(w1.v, ones, accS, 0, 0, 0);
  }

  // epilogue: reduce 4 wave K-partials, divide, write final output
#pragma unroll
  for (int nf = 0; nf < 4; ++nf)
#pragma unroll
    for (int rgi = 0; rgi < 4; ++rgi)
      pb[(wv * 16 + quad * 4 + rgi) * 68 + nf * 16 + tn] = acc[nf][rgi];
  if (tn == 0) {
#pragma unroll
    for (int rgi = 0; rgi < 4; ++rgi)
      sb[wv * 16 + quad * 4 + rgi] = accS[rgi];
  }
  __syncthreads();
  for (int t = tid; t < 16 * OD; t += 256) {
    int rr = t >> 6, cc = t & 63;
    float num = pb[(0 * 16 + rr) * 68 + cc] + pb[(1 * 16 + rr) * 68 + cc] +
                pb[(2 * 16 + rr) * 68 + cc] + pb[(3 * 16 + rr) * 68 + cc];
    float den = sb[0 * 16 + rr] + sb[1 * 16 + rr] + sb[2 * 16 + rr] + sb[3 * 16 + rr];
    out[((long)(i0 + rr)) * OD + cc] = num / den;
  }
}

extern "C" void kernel_launch(void* const* d_in, const int* in_sizes, int n_in,
                              void* d_out, int out_size, void* d_ws, size_t ws_size,
                              hipStream_t stream) {
  const float* input = (const float*)d_in[0];
  const int* adj     = (const int*)d_in[1];
  const float* W     = (const float*)d_in[2];
  const float* a     = (const float*)d_in[3];
  float* out = (float*)d_out;

  char* ws = (char*)d_ws;
  __hip_bfloat16* hTt = (__hip_bfloat16*)ws;              // 1 MB (tiled)
  float* f1p = (float*)(ws + (size_t)OD * GN * 2);        // 32 KB
  float* f2p = f1p + GN;                                  // 32 KB

  gat_k1<<<128, 256, 0, stream>>>(input, W, a, hTt, f1p, f2p, out);
  gat_k2<<<512, 256, 0, stream>>>(adj, hTt, f1p, f2p, out);
}

// Round 3
// 390.392 us; speedup vs baseline: 1.1004x; 1.1004x over previous
//
#include <hip/hip_runtime.h>
#include <hip/hip_bf16.h>

#define GN 8192
#define KD 256
#define OD 64
#define LOG2E 1.44269504f
#define ASTR 260   // adj LDS row stride (ints): 1040B, 16B-aligned, 2-way alias (free)
#define NCH 16     // 16 chunks x 256 j = 4096-j slice per block

typedef __attribute__((ext_vector_type(8))) short bf16x8;
typedef __attribute__((ext_vector_type(4))) float f32x4;

__device__ __forceinline__ float fexp2(float x) {
#if __has_builtin(__builtin_amdgcn_exp2f)
  return __builtin_amdgcn_exp2f(x);
#else
  return exp2f(x);
#endif
}

// ---------------------------------------------------------------------------
// Kernel 1: h = input @ W (fp32). Emits hTt (bf16, TILED [j/32][col][j%32] so
// k2's B-frag loads are contiguous 1KB bursts), f1p/f2p fp32 pre-scaled by
// log2(e), and the 3 scalar e-outputs.
// R2 lesson: do NOT replace the LDS-staged W with wave-uniform s_loads (64KB
// W thrashes the 16KB scalar cache at 2 waves/CU). This structure = ~13 us.
// ---------------------------------------------------------------------------
__global__ __launch_bounds__(256) void gat_k1(
    const float* __restrict__ input, const float* __restrict__ W,
    const float* __restrict__ a, __hip_bfloat16* __restrict__ hTt,
    float* __restrict__ f1p, float* __restrict__ f2p, float* __restrict__ out)
{
  __shared__ float Wl[KD * OD];        // 64 KB, [k][c]
  __shared__ float inT[KD * 33];       // [k][r], pad 33
  __shared__ float red1[8][32];
  __shared__ float red2[8][32];
  __shared__ float s1row[32];
  __shared__ float s2row[32];

  const int tid = threadIdx.x;
  const int i0 = blockIdx.x * 32;      // this block's 32 j-rows == one j-tile

  for (int idx = tid; idx < KD * OD / 4; idx += 256)
    ((float4*)Wl)[idx] = ((const float4*)W)[idx];

#pragma unroll
  for (int it = 0; it < 8; ++it) {
    int idx = tid + it * 256;
    int r = idx >> 6, k4 = idx & 63;
    float4 v = *(const float4*)(input + (long)(i0 + r) * KD + k4 * 4);
    inT[(k4 * 4 + 0) * 33 + r] = v.x;
    inT[(k4 * 4 + 1) * 33 + r] = v.y;
    inT[(k4 * 4 + 2) * 33 + r] = v.z;
    inT[(k4 * 4 + 3) * 33 + r] = v.w;
  }
  __syncthreads();

  const int r = tid & 31;
  const int cg = tid >> 5;
  float acc[8];
#pragma unroll
  for (int c = 0; c < 8; ++c) acc[c] = 0.f;

#pragma unroll 4
  for (int k = 0; k < KD; ++k) {
    float inv = inT[k * 33 + r];
    float4 wa = *(const float4*)&Wl[k * 64 + cg * 8];
    float4 wb = *(const float4*)&Wl[k * 64 + cg * 8 + 4];
    acc[0] += inv * wa.x; acc[1] += inv * wa.y;
    acc[2] += inv * wa.z; acc[3] += inv * wa.w;
    acc[4] += inv * wb.x; acc[5] += inv * wb.y;
    acc[6] += inv * wb.z; acc[7] += inv * wb.w;
  }

  // hTt[jtile = i0/32][col][jw = r], two 16-j sub-tiles per 32: store as
  // [jt32][col][j%32] contiguous.
#pragma unroll
  for (int c = 0; c < 8; ++c)
    hTt[(long)blockIdx.x * (OD * 32) + (cg * 8 + c) * 32 + r] =
        __float2bfloat16(acc[c]);

  float s1 = 0.f, s2 = 0.f;
#pragma unroll
  for (int c = 0; c < 8; ++c) {
    s1 += acc[c] * a[cg * 8 + c];
    s2 += acc[c] * a[OD + cg * 8 + c];
  }
  red1[cg][r] = s1; red2[cg][r] = s2;
  __syncthreads();
  if (tid < 32) {
    float f1 = 0.f, f2 = 0.f;
#pragma unroll
    for (int g = 0; g < 8; ++g) { f1 += red1[g][tid]; f2 += red2[g][tid]; }
    s1row[tid] = f1; s2row[tid] = f2;
    f1p[i0 + tid] = f1 * LOG2E;
    f2p[i0 + tid] = f2 * LOG2E;
  }
  __syncthreads();
  if (blockIdx.x == 0 && tid == 0) {
    float e12 = s1row[1] + s2row[2];
    float e13 = s1row[1] + s2row[3];
    float e32 = s1row[3] + s2row[2];
    out[(long)GN * OD + 0] = fmaxf(e12, 0.01f * e12);
    out[(long)GN * OD + 1] = fmaxf(e13, 0.01f * e13);
    out[(long)GN * OD + 2] = fmaxf(e32, 0.01f * e32);
  }
}

// ---------------------------------------------------------------------------
// Kernel 2: fused mask+softmax(no-max)+alpha@h over a 4096-j slice.
// r4-proven LDS double-buffer staging of adj + two fixes:
//  (1) B-frags from TILED hTt -> each load is a contiguous 1KB burst;
//  (2) per-chunk vmem issue order: B(c) FIRST, then adj prefetch(c+1), so
//      the fine-grained vmcnt wait for B(c) leaves the prefetch in flight.
// f2 slice staged to LDS once. 1024 blocks = 512 rowgroups x 2 j-slices,
// 3 blocks/CU. Partial num/den to gmem; k3 combines.
// R1/R2 lessons: barrier-free direct-load variant is perf-neutral (adj-BW
// envelope), full-row 512-block variant regresses (halves in-flight loads).
// This 1024-block staged form is the best-measured configuration.
// ---------------------------------------------------------------------------
__global__ __launch_bounds__(256, 3) void gat_k2(
    const int* __restrict__ adj, const __hip_bfloat16* __restrict__ hTt,
    const float* __restrict__ f1p, const float* __restrict__ f2p,
    float* __restrict__ pn, float* __restrict__ pd)
{
  __shared__ int abuf[2][16 * ASTR];   // 33.3 KB staged adj (dbuf)
  __shared__ float f2l[4096];          // 16 KB f2 slice
  // epilogue overlays partial buffers on abuf:
  float* pb = (float*)abuf;            // [4][16][68]
  float* sb = pb + 4 * 16 * 68;        // [4][16]

  const int tid = threadIdx.x;
  const int lane = tid & 63;
  const int wv = tid >> 6;             // wave -> k-steps {2wv, 2wv+1}
  const int tn = lane & 15;
  const int quad = lane >> 4;
  const int rg = blockIdx.x >> 1;
  const int js = blockIdx.x & 1;
  const int i0 = rg * 16;
  const int jbase = js * 4096;

  // stage f2 slice (16 KB)
  for (int i = tid; i < 4096 / 4; i += 256)
    ((float4*)f2l)[i] = ((const float4*)(f2p + jbase))[i];

  const float f1r = f1p[i0 + tn];

  // adj staging assignment: thread -> row sr, columns sc + 64k
  const int sr = tid >> 4;
  const int sc = (tid & 15) * 4;
  const int* gsrc = adj + (long)(i0 + sr) * GN + jbase + sc;

  // per-wave j-offsets within a 256-j chunk
  const int jo0 = wv * 64 + quad * 8;
  const int jo1 = jo0 + 32;
  // B-frag lane base inside a 32-j hTt slice
  const __hip_bfloat16* hsl = hTt + (long)(jbase / 32) * (OD * 32) + tn * 32 + quad * 8;

  f32x4 acc[4];
#pragma unroll
  for (int nf = 0; nf < 4; ++nf) acc[nf] = (f32x4){0.f, 0.f, 0.f, 0.f};
  f32x4 accS = (f32x4){0.f, 0.f, 0.f, 0.f};

  bf16x8 ones;  // ones in column n==0 -> row sums via MFMA
  {
    short ov = (tn == 0) ? (short)0x3F80 : (short)0;
#pragma unroll
    for (int i = 0; i < 8; ++i) ones[i] = ov;
  }

  int4 st[4];
  // prologue: stage chunk 0
#pragma unroll
  for (int k = 0; k < 4; ++k) st[k] = *(const int4*)(gsrc + 64 * k);
#pragma unroll
  for (int k = 0; k < 4; ++k) *(int4*)&abuf[0][sr * ASTR + sc + 64 * k] = st[k];
  __syncthreads();

  for (int c = 0; c < NCH; ++c) {
    const int cur = c & 1, nxt = cur ^ 1;

    // (1) B(c) loads FIRST: contiguous 1KB bursts from tiled hTt (L2-resident)
    const __hip_bfloat16* h0 = hsl + (long)(c * 8 + 2 * wv) * (OD * 32);
    const __hip_bfloat16* h1 = h0 + (OD * 32);
    bf16x8 B0[4], B1[4];
#pragma unroll
    for (int nf = 0; nf < 4; ++nf) {
      B0[nf] = *(const bf16x8*)(h0 + nf * (16 * 32));
      B1[nf] = *(const bf16x8*)(h1 + nf * (16 * 32));
    }

    // (2) THEN adj prefetch for chunk c+1 (stays in flight across B-waits)
    if (c + 1 < NCH) {
#pragma unroll
      for (int k = 0; k < 4; ++k)
        st[k] = *(const int4*)(gsrc + (c + 1) * 256 + 64 * k);
    }

    // A-source adj + f2 from LDS
    const int4 a0 = *(const int4*)&abuf[cur][tn * ASTR + jo0];
    const int4 a1 = *(const int4*)&abuf[cur][tn * ASTR + jo0 + 4];
    const int4 a2 = *(const int4*)&abuf[cur][tn * ASTR + jo1];
    const int4 a3 = *(const int4*)&abuf[cur][tn * ASTR + jo1 + 4];
    const float4 f20 = *(const float4*)&f2l[c * 256 + jo0];
    const float4 f21 = *(const float4*)&f2l[c * 256 + jo0 + 4];
    const float4 f22 = *(const float4*)&f2l[c * 256 + jo1];
    const float4 f23 = *(const float4*)&f2l[c * 256 + jo1 + 4];

    union { bf16x8 v; unsigned u[4]; } w0, w1;
    {
      float e0 = f1r + f20.x, e1 = f1r + f20.y, e2 = f1r + f20.z, e3 = f1r + f20.w;
      float e4 = f1r + f21.x, e5 = f1r + f21.y, e6 = f1r + f21.z, e7 = f1r + f21.w;
      float v0 = fexp2((a0.x > 0) ? fmaxf(e0, 0.01f * e0) : -256.f);
      float v1 = fexp2((a0.y > 0) ? fmaxf(e1, 0.01f * e1) : -256.f);
      float v2 = fexp2((a0.z > 0) ? fmaxf(e2, 0.01f * e2) : -256.f);
      float v3 = fexp2((a0.w > 0) ? fmaxf(e3, 0.01f * e3) : -256.f);
      float v4 = fexp2((a1.x > 0) ? fmaxf(e4, 0.01f * e4) : -256.f);
      float v5 = fexp2((a1.y > 0) ? fmaxf(e5, 0.01f * e5) : -256.f);
      float v6 = fexp2((a1.z > 0) ? fmaxf(e6, 0.01f * e6) : -256.f);
      float v7 = fexp2((a1.w > 0) ? fmaxf(e7, 0.01f * e7) : -256.f);
      w0.u[0] = __builtin_amdgcn_perm(__float_as_uint(v1), __float_as_uint(v0), 0x07060302u);
      w0.u[1] = __builtin_amdgcn_perm(__float_as_uint(v3), __float_as_uint(v2), 0x07060302u);
      w0.u[2] = __builtin_amdgcn_perm(__float_as_uint(v5), __float_as_uint(v4), 0x07060302u);
      w0.u[3] = __builtin_amdgcn_perm(__float_as_uint(v7), __float_as_uint(v6), 0x07060302u);
    }
    {
      float e0 = f1r + f22.x, e1 = f1r + f22.y, e2 = f1r + f22.z, e3 = f1r + f22.w;
      float e4 = f1r + f23.x, e5 = f1r + f23.y, e6 = f1r + f23.z, e7 = f1r + f23.w;
      float v0 = fexp2((a2.x > 0) ? fmaxf(e0, 0.01f * e0) : -256.f);
      float v1 = fexp2((a2.y > 0) ? fmaxf(e1, 0.01f * e1) : -256.f);
      float v2 = fexp2((a2.z > 0) ? fmaxf(e2, 0.01f * e2) : -256.f);
      float v3 = fexp2((a2.w > 0) ? fmaxf(e3, 0.01f * e3) : -256.f);
      float v4 = fexp2((a3.x > 0) ? fmaxf(e4, 0.01f * e4) : -256.f);
      float v5 = fexp2((a3.y > 0) ? fmaxf(e5, 0.01f * e5) : -256.f);
      float v6 = fexp2((a3.z > 0) ? fmaxf(e6, 0.01f * e6) : -256.f);
      float v7 = fexp2((a3.w > 0) ? fmaxf(e7, 0.01f * e7) : -256.f);
      w1.u[0] = __builtin_amdgcn_perm(__float_as_uint(v1), __float_as_uint(v0), 0x07060302u);
      w1.u[1] = __builtin_amdgcn_perm(__float_as_uint(v3), __float_as_uint(v2), 0x07060302u);
      w1.u[2] = __builtin_amdgcn_perm(__float_as_uint(v5), __float_as_uint(v4), 0x07060302u);
      w1.u[3] = __builtin_amdgcn_perm(__float_as_uint(v7), __float_as_uint(v6), 0x07060302u);
    }

#pragma unroll
    for (int nf = 0; nf < 4; ++nf)
      acc[nf] = __builtin_amdgcn_mfma_f32_16x16x32_bf16(w0.v, B0[nf], acc[nf], 0, 0, 0);
    accS = __builtin_amdgcn_mfma_f32_16x16x32_bf16(w0.v, ones, accS, 0, 0, 0);
#pragma unroll
    for (int nf = 0; nf < 4; ++nf)
      acc[nf] = __builtin_amdgcn_mfma_f32_16x16x32_bf16(w1.v, B1[nf], acc[nf], 0, 0, 0);
    accS = __builtin_amdgcn_mfma_f32_16x16x32_bf16(w1.v, ones, accS, 0, 0, 0);

    if (c + 1 < NCH) {  // commit staged chunk c+1 (waits only on its own loads)
#pragma unroll
      for (int k = 0; k < 4; ++k)
        *(int4*)&abuf[nxt][sr * ASTR + sc + 64 * k] = st[k];
    }
    __syncthreads();
  }

  // epilogue: reduce the 4 wave K-partials in LDS (overlaid), write partials
#pragma unroll
  for (int nf = 0; nf < 4; ++nf)
#pragma unroll
    for (int rgi = 0; rgi < 4; ++rgi)
      pb[(wv * 16 + quad * 4 + rgi) * 68 + nf * 16 + tn] = acc[nf][rgi];
  if (tn == 0) {
#pragma unroll
    for (int rgi = 0; rgi < 4; ++rgi)
      sb[wv * 16 + quad * 4 + rgi] = accS[rgi];
  }
  __syncthreads();
  for (int t = tid; t < 16 * OD; t += 256) {
    int rr = t >> 6, cc = t & 63;
    float num = pb[(0 * 16 + rr) * 68 + cc] + pb[(1 * 16 + rr) * 68 + cc] +
                pb[(2 * 16 + rr) * 68 + cc] + pb[(3 * 16 + rr) * 68 + cc];
    pn[((long)js * GN + i0 + rr) * OD + cc] = num;
  }
  if (tid < 16) {
    float den = sb[0 * 16 + tid] + sb[1 * 16 + tid] + sb[2 * 16 + tid] + sb[3 * 16 + tid];
    pd[(long)js * GN + i0 + tid] = den;
  }
}

// ---------------------------------------------------------------------------
// Kernel 3: combine the 2 j-slices: out = (pn0+pn1)/(pd0+pd1)
// ---------------------------------------------------------------------------
__global__ __launch_bounds__(256) void gat_k3(
    const float* __restrict__ pn, const float* __restrict__ pd,
    float* __restrict__ out)
{
  long t = (long)blockIdx.x * 256 + threadIdx.x;   // 0 .. GN*OD
  int i = (int)(t >> 6);
  float num = pn[t] + pn[(long)GN * OD + t];
  float den = pd[i] + pd[GN + i];
  out[t] = num / den;
}

extern "C" void kernel_launch(void* const* d_in, const int* in_sizes, int n_in,
                              void* d_out, int out_size, void* d_ws, size_t ws_size,
                              hipStream_t stream) {
  const float* input = (const float*)d_in[0];
  const int* adj     = (const int*)d_in[1];
  const float* W     = (const float*)d_in[2];
  const float* a     = (const float*)d_in[3];
  float* out = (float*)d_out;

  char* ws = (char*)d_ws;
  __hip_bfloat16* hTt = (__hip_bfloat16*)ws;              // 1 MB (tiled)
  float* f1p = (float*)(ws + (size_t)OD * GN * 2);        // 32 KB
  float* f2p = f1p + GN;                                  // 32 KB
  float* pn  = f2p + GN;                                  // 4 MB
  float* pd  = pn + (size_t)2 * GN * OD;                  // 64 KB

  gat_k1<<<256, 256, 0, stream>>>(input, W, a, hTt, f1p, f2p, out);
  gat_k2<<<1024, 256, 0, stream>>>(adj, hTt, f1p, f2p, pn, pd);
  gat_k3<<<GN * OD / 256, 256, 0, stream>>>(pn, pd, out);
}